// Round 4
// baseline (949.664 us; speedup 1.0000x reference)
//
#include <hip/hip_runtime.h>
#include <hip/hip_fp16.h>
#include <stdint.h>

// Problem: B=4, S=2048, IN=4096, OUT=12288
//   x      : const float*  (fp16 promoted)   [8192][4096]
//   w_q    : const int*    (int8 in int32)   [12288][4096]
//   w_scale: const float*  [12288]
//   bias   : const float*  (fp16 promoted)   [12288]
//   out    : float*        [8192][12288]
#define M_TOK 8192
#define K_IN  4096
#define N_OUT 12288

typedef int v4i_t __attribute__((ext_vector_type(4)));

// async global->LDS, 16B/lane. LDS dest = wave-uniform base + lane*16 (HW).
__device__ __forceinline__ void load_lds16(const void* g, void* l) {
    __builtin_amdgcn_global_load_lds(
        (const __attribute__((address_space(1))) unsigned int*)g,
        (__attribute__((address_space(3))) unsigned int*)l, 16, 0, 0);
}

// ---------------- fused: pack w (int32->int8) + per-token dynamic quant ----------------
#define PACK_BLOCKS 2048
#define PACK_ITERS  24   // PACK_BLOCKS*256*PACK_ITERS == N_OUT*K_IN/4 == 12582912

__global__ __launch_bounds__(256) void prep_kernel(
    const int* __restrict__ wsrc, uint32_t* __restrict__ wdst,
    const float* __restrict__ x, int8_t* __restrict__ xq, float* __restrict__ xs) {
    const int tid = threadIdx.x;
    const int bid = blockIdx.x;
    if (bid < PACK_BLOCKS) {
        size_t i = (size_t)bid * 256 + tid;
#pragma unroll
        for (int it = 0; it < PACK_ITERS; ++it, i += (size_t)PACK_BLOCKS * 256) {
            const int4 v = ((const int4*)wsrc)[i];
            wdst[i] = (uint32_t)(uint8_t)(int8_t)v.x
                    | ((uint32_t)(uint8_t)(int8_t)v.y << 8)
                    | ((uint32_t)(uint8_t)(int8_t)v.z << 16)
                    | ((uint32_t)(uint8_t)(int8_t)v.w << 24);
        }
        return;
    }
    const int token = bid - PACK_BLOCKS;
    const float4* src = (const float4*)(x + (size_t)token * K_IN);
    float v[16];
#pragma unroll
    for (int c = 0; c < 4; ++c) {
        float4 p = src[c * 256 + tid];
        v[c * 4 + 0] = p.x; v[c * 4 + 1] = p.y;
        v[c * 4 + 2] = p.z; v[c * 4 + 3] = p.w;
    }
    float amax = 0.f;
#pragma unroll
    for (int i = 0; i < 16; ++i) amax = fmaxf(amax, fabsf(v[i]));
#pragma unroll
    for (int off = 32; off >= 1; off >>= 1)
        amax = fmaxf(amax, __shfl_xor(amax, off));
    __shared__ float wmax[4];
    const int wave = tid >> 6, lane = tid & 63;
    if (lane == 0) wmax[wave] = amax;
    __syncthreads();
    amax = fmaxf(fmaxf(wmax[0], wmax[1]), fmaxf(wmax[2], wmax[3]));
    const float scale = fmaxf(amax, 1e-6f) / 127.0f;  // exact div, matches np
    if (tid == 0) xs[token] = scale;

    uint32_t* dst = (uint32_t*)(xq + (size_t)token * K_IN);
#pragma unroll
    for (int c = 0; c < 4; ++c) {
        uint32_t w = 0;
#pragma unroll
        for (int e = 0; e < 4; ++e) {
            float r = rintf(v[c * 4 + e] / scale);   // half-to-even, matches jnp.round
            r = fminf(fmaxf(r, -128.f), 127.f);
            w |= (uint32_t)(uint8_t)(int8_t)(int)r << (8 * e);
        }
        dst[c * 256 + tid] = w;
    }
}

// ---------------- int8 GEMM: 256x256 tile, BK=128B, 8 waves, 1-barrier/phase, reg-prefetch --------
// LDS 128KiB: A[2buf][2kk][256 rows][64B] at 0, B same at 65536. Half-tile h staged at phase h-5.
// Phase p = 4T+PH: [issue ds_reads(p+1) into reg buf[(p+1)&1] | stage(h=p+5) |
//                   lgkmcnt(K=#just-issued, in-order DS => reads(p) done) | 16 MFMA on buf[p&1] |
//                   ckpt | s_barrier].  Fragment reads get a full-phase (~1100cy) head start and
// the LDS port serves them under the MFMA window (64KB/CU/phase @128B/cy = 500cy < 653cy MFMA).
// Ledger (re-derived for prefetch; ckpt values unchanged from r3's verified ledger):
//  * publish: reads(p2) issue after barrier(end-p0); halves 4T+2,3 drained at ckpt end-p0. ✓
//             reads(p0,T+1) issue after barrier(end-p2); halves 4T+4,5 drained at ckpt end-p2. ✓
//  * overwrite: slab last lgkm-waited phase 4T+1; overwriting stage at phase 4T+3 after
//             barrier(end 4T+2) => >=1 barrier gap, all streams. ✓
//  * lgkm K: PH0->4, PH1->8, PH2->4, PH3->8; final peeled phase -> 0.
//  * ckpt: end-p0 vmcnt(4) (T=31: 0); end-p2 vmcnt(4) (T=31: none). Cover ~5 phases >> HBM 900cy.
// Swizzle (verified r1: BANK_CONFLICT=0): linear LDS dest + involution source + same on read.
// Block->tile map (verified r2: FETCH 825->296MB): XCD band by=xcd*4+(r&3), bx=g*8+(r>>2).
__global__ __launch_bounds__(512, 2) void gemm_kernel(
    const int8_t* __restrict__ xq, const float* __restrict__ xs,
    const int8_t* __restrict__ wq, const float* __restrict__ wscale,
    const float* __restrict__ bias, float* __restrict__ out) {
    extern __shared__ char smem[];

    const int tid  = threadIdx.x;
    const int wid  = tid >> 6, lane = tid & 63;
    const int wr   = wid >> 2, wc = wid & 3;   // 2M x 4N waves; wave output 128x64

    const int bid = blockIdx.x;
    const int xcd = bid & 7;
    const int s   = bid >> 3;        // 0..191
    const int g   = s >> 5;          // 0..5
    const int r_  = s & 31;
    const int by  = xcd * 4 + (r_ & 3);
    const int bx  = g * 8 + (r_ >> 2);
    const int m0  = by * 256, n0 = bx * 256;

    const int8_t* Ag = xq + (size_t)m0 * K_IN;
    const int8_t* Bg = wq + (size_t)n0 * K_IN;

    // staging source pre-swizzle: row bit0<->bit2 swap + granule XOR (l>>1)&3
    const int rl = (lane >> 2) & 15;
    const int rg = (rl & 0xA) | ((rl & 1) << 2) | ((rl >> 2) & 1);
    const size_t rowByte = (size_t)(wid * 16 + rg) * K_IN;
    const int gsw16 = ((lane & 3) ^ ((lane >> 3) & 3)) << 4;

    // fragment read offset: A[m=lane&15][k=(lane>>4)*16+j]; same involution
    const int fr = lane & 15, fq = lane >> 4;
    const int sfr = (fr & 0xA) | ((fr & 1) << 2) | ((fr >> 2) & 1);
    const int frOff = sfr * 64 + (((fq ^ (sfr >> 1)) & 3) << 4);

    auto stage_half = [&](int h) {
        const int th = h >> 2, r = h & 3;
        const int isB = r & 1, kk = r >> 1;
        const int8_t* G = isB ? Bg : Ag;
        char* lb = smem + (isB << 16) + ((((th & 1) << 1) | kk) << 14) + (wid << 10);
        const int8_t* g0 = G + rowByte + th * 128 + (kk << 6) + gsw16;
        load_lds16(g0, lb);
        load_lds16(g0 + (size_t)128 * K_IN, lb + 8192);
    };

    v4i_t acc[8][4] = {};
    v4i_t af[2][4], bf[2][4];   // double-buffered fragments; all indices compile-time

#define ISSUE_BF(bufb_, slab_)                                                         \
    _Pragma("unroll")                                                                  \
    for (int j = 0; j < 4; ++j)                                                        \
        bf[bufb_][j] = *(const v4i_t*)(smem + 65536 + (slab_) + (wc << 12) + frOff + (j << 10));

#define ISSUE_AF(bufa_, slab_, ioff_)                                                  \
    _Pragma("unroll")                                                                  \
    for (int i = 0; i < 4; ++i)                                                        \
        af[bufa_][i] = *(const v4i_t*)(smem + (slab_) + (wr << 13) + frOff + (((ioff_) + i) << 10));

    // prologue: halves 0..4 (10 loads); drain h0,h1 -> vmcnt(6); then prefetch phase-0 frags
#pragma unroll
    for (int h = 0; h < 5; ++h) stage_half(h);
    asm volatile("s_waitcnt vmcnt(6)" ::: "memory");
    __builtin_amdgcn_sched_barrier(0);
    __builtin_amdgcn_s_barrier();
    __builtin_amdgcn_sched_barrier(0);
    ISSUE_BF(0, 0)
    ISSUE_AF(0, 0, 0)

// one phase: PH in {0,1,2,3}; kk = PH>>1; acc rows (PH&1)*4.. ; LAST = (T==31).
#define PHASE(T_, PH_, LAST_)                                                          \
    {                                                                                  \
        if (!((LAST_) && (PH_) == 3)) {                                                \
            const int nT_   = ((PH_) == 3) ? (T_) + 1 : (T_);                          \
            const int nPH_  = ((PH_) + 1) & 3;                                         \
            const int slabN_ = ((((nT_) & 1) << 1) | (nPH_ >> 1)) << 14;               \
            if ((nPH_ & 1) == 0) { ISSUE_BF(nPH_ >> 1, slabN_) }                       \
            ISSUE_AF(nPH_ & 1, slabN_, (nPH_ & 1) * 4)                                 \
        }                                                                              \
        const int hs_ = 4 * (T_) + 5 + (PH_);                                          \
        if (hs_ < 128) stage_half(hs_);                                                \
        if ((LAST_) && (PH_) == 3)                                                     \
            asm volatile("s_waitcnt lgkmcnt(0)" ::: "memory");                         \
        else if (((PH_) & 1) == 1)                                                     \
            asm volatile("s_waitcnt lgkmcnt(8)" ::: "memory");                         \
        else                                                                           \
            asm volatile("s_waitcnt lgkmcnt(4)" ::: "memory");                         \
        __builtin_amdgcn_sched_barrier(0);                                             \
        __builtin_amdgcn_s_setprio(1);                                                 \
        _Pragma("unroll")                                                              \
        for (int i = 0; i < 4; ++i)                                                    \
            _Pragma("unroll")                                                          \
            for (int j = 0; j < 4; ++j)                                                \
                acc[((PH_) & 1) * 4 + i][j] = __builtin_amdgcn_mfma_i32_16x16x64_i8(   \
                    af[(PH_) & 1][i], bf[(PH_) >> 1][j], acc[((PH_) & 1) * 4 + i][j], 0, 0, 0); \
        __builtin_amdgcn_s_setprio(0);                                                 \
        if ((PH_) == 0) {                                                              \
            if (LAST_) asm volatile("s_waitcnt vmcnt(0)" ::: "memory");                \
            else       asm volatile("s_waitcnt vmcnt(4)" ::: "memory");                \
            __builtin_amdgcn_sched_barrier(0);                                         \
        }                                                                              \
        if ((PH_) == 2 && !(LAST_)) {                                                  \
            asm volatile("s_waitcnt vmcnt(4)" ::: "memory");                           \
            __builtin_amdgcn_sched_barrier(0);                                         \
        }                                                                              \
        __builtin_amdgcn_sched_barrier(0);                                             \
        __builtin_amdgcn_s_barrier();                                                  \
        __builtin_amdgcn_sched_barrier(0);                                             \
    }

    for (int T = 0; T < 31; ++T) {
        PHASE(T, 0, false)
        PHASE(T, 1, false)
        PHASE(T, 2, false)
        PHASE(T, 3, false)
    }
    // peeled T=31 tail
    PHASE(31, 0, true)
    PHASE(31, 1, true)
    PHASE(31, 2, true)
    PHASE(31, 3, true)
#undef PHASE
#undef ISSUE_BF
#undef ISSUE_AF

    // epilogue: C/D layout col=lane&15, row=(lane>>4)*4+reg (verified in prior rounds)
    const int col = lane & 15, rq = lane >> 4;
#pragma unroll
    for (int i = 0; i < 8; ++i) {
        const int mb = m0 + wr * 128 + i * 16 + rq * 4;
        float xsv[4];
#pragma unroll
        for (int r = 0; r < 4; ++r) xsv[r] = xs[mb + r];
#pragma unroll
        for (int j = 0; j < 4; ++j) {
            const int n = n0 + wc * 64 + j * 16 + col;
            const float ws = wscale[n];
            const float bv = bias[n];
#pragma unroll
            for (int r = 0; r < 4; ++r) {
                float o = (float)acc[i][j][r] * xsv[r] * ws + bv;
                o = __half2float(__float2half(o));   // match ref's final .astype(float16)
                out[(size_t)(mb + r) * N_OUT + n] = o;
            }
        }
    }
}

extern "C" void kernel_launch(void* const* d_in, const int* in_sizes, int n_in,
                              void* d_out, int out_size, void* d_ws, size_t ws_size,
                              hipStream_t stream) {
    const float* x      = (const float*)d_in[0];
    const int*   wq32   = (const int*)d_in[1];
    const float* wscale = (const float*)d_in[2];
    const float* bias   = (const float*)d_in[3];
    float* out = (float*)d_out;

    int8_t* xq  = (int8_t*)d_ws;                                            // 32 MiB
    float*  xs  = (float*)((char*)d_ws + (size_t)M_TOK * K_IN);             // 32 KiB
    int8_t* wq8 = (int8_t*)((char*)d_ws + (size_t)M_TOK * K_IN + 65536);    // 48 MiB

    static bool attrDone = false;
    if (!attrDone) {
        (void)hipFuncSetAttribute((const void*)gemm_kernel,
                                  hipFuncAttributeMaxDynamicSharedMemorySize, 131072);
        attrDone = true;
    }

    prep_kernel<<<PACK_BLOCKS + M_TOK, 256, 0, stream>>>(wq32, (uint32_t*)wq8, x, xq, xs);

    gemm_kernel<<<dim3(1536), dim3(512), 131072, stream>>>(xq, xs, wq8, wscale, bias, out);
}